// Round 15
// baseline (196.291 us; speedup 1.0000x reference)
//
#include <hip/hip_runtime.h>
#include <hip/hip_bf16.h>
#include <math.h>

#define L_SEQ 2048
#define NB 2
#define DM 1024
#define NHEAD 16
#define HDIM 64
#define QKV_LD 3072
#define RL 0.18033688011112042f   // 0.125 * log2(e)
#define DTHR 44.3614f             // 8 / RL  (defer-max threshold in raw score units)

typedef __attribute__((ext_vector_type(8))) __bf16 bf16x8;
typedef __attribute__((ext_vector_type(4))) __bf16 bf16x4;
typedef __attribute__((ext_vector_type(4))) float f32x4;
typedef __attribute__((ext_vector_type(16))) float f32x16;
typedef __attribute__((ext_vector_type(4))) unsigned int u32x4;

typedef __attribute__((address_space(3))) unsigned int lds_u32;
typedef const __attribute__((address_space(1))) unsigned int glob_u32;
#define GLD16(g, l) __builtin_amdgcn_global_load_lds((glob_u32*)(g), (lds_u32*)(l), 16, 0, 0)

__device__ __forceinline__ unsigned pack2(float a, float b) {
  unsigned short ua = __builtin_bit_cast(unsigned short, (__bf16)a);
  unsigned short ub = __builtin_bit_cast(unsigned short, (__bf16)b);
  return (unsigned)ua | ((unsigned)ub << 16);
}

// ---------------- fused prep: 4 weight transposes + x convert ----------------
__global__ __launch_bounds__(256) void prep_k(const float* __restrict__ w_qkv,
                                              const float* __restrict__ w_out,
                                              const float* __restrict__ w1,
                                              const float* __restrict__ w2,
                                              const float* __restrict__ x,
                                              __hip_bfloat16* __restrict__ wqT,
                                              __hip_bfloat16* __restrict__ woT,
                                              __hip_bfloat16* __restrict__ w1T,
                                              __hip_bfloat16* __restrict__ w2T,
                                              __hip_bfloat16* __restrict__ xb) {
  const int id = blockIdx.x;
  if (id >= 8192) {                     // x f32 -> bf16
    const size_t base = ((size_t)(id - 8192) * 256 + threadIdx.x) * 8;
    float4 a = *reinterpret_cast<const float4*>(x + base);
    float4 b = *reinterpret_cast<const float4*>(x + base + 4);
    bf16x8 o;
    o[0] = (__bf16)a.x; o[1] = (__bf16)a.y; o[2] = (__bf16)a.z; o[3] = (__bf16)a.w;
    o[4] = (__bf16)b.x; o[5] = (__bf16)b.y; o[6] = (__bf16)b.z; o[7] = (__bf16)b.w;
    *reinterpret_cast<bf16x8*>(xb + base) = o;
    return;
  }
  const float* W; __hip_bfloat16* WT; int K, N, kb, nb;
  if (id < 3072)      { W = w_qkv; WT = wqT; K = 1024; N = 3072; kb = id & 31;          nb = id >> 5; }
  else if (id < 4096) { W = w_out; WT = woT; K = 1024; N = 1024; kb = (id - 3072) & 31; nb = (id - 3072) >> 5; }
  else if (id < 6144) { W = w1;    WT = w1T; K = 1024; N = 2048; kb = (id - 4096) & 31; nb = (id - 4096) >> 5; }
  else                { W = w2;    WT = w2T; K = 2048; N = 1024; kb = (id - 6144) & 63; nb = (id - 6144) >> 6; }
  __shared__ float tsm[32][33];
  const int k0 = kb * 32, n0 = nb * 32;
  const int c = threadIdx.x & 31, r = threadIdx.x >> 5;
#pragma unroll
  for (int i = 0; i < 4; ++i)
    tsm[r + 8 * i][c] = W[(size_t)(k0 + r + 8 * i) * N + n0 + c];
  __syncthreads();
#pragma unroll
  for (int i = 0; i < 4; ++i)
    WT[(size_t)(n0 + r + 8 * i) * K + k0 + c] = __float2bfloat16(tsm[c][r + 8 * i]);
}

// ---------------- GEMM v2: BK=64, both-sides XOR swizzle, XCD block swizzle ----------------
template<int EPI, int OUTB, int HASRES, int BN>
__global__ __launch_bounds__(256) void gemm2(const __hip_bfloat16* __restrict__ A,
                                             const __hip_bfloat16* __restrict__ BT,
                                             const float* __restrict__ bias,
                                             float* __restrict__ Cf,
                                             __hip_bfloat16* __restrict__ Cb,
                                             const float* __restrict__ RESF,
                                             const __hip_bfloat16* __restrict__ RESB,
                                             int M, int N, int K) {
  constexpr int MI = (BN == 128) ? 4 : 2;
  __shared__ __align__(16) __hip_bfloat16 As[128 * 64];
  __shared__ __align__(16) __hip_bfloat16 Bs[BN * 64];
  const int tid  = threadIdx.x;
  const int lane = tid & 63, wave = tid >> 6;
  const int wr = (BN == 128) ? (wave >> 1) : wave;
  const int wc = (BN == 128) ? (wave & 1) : 0;
  const int lr = lane & 15, lq = lane >> 4;
  unsigned g = blockIdx.y * gridDim.x + blockIdx.x;
  const unsigned cpx = (gridDim.x * gridDim.y) >> 3;
  g = (g & 7) * cpx + (g >> 3);
  const int bm0 = (int)(g / gridDim.x) * 128;
  const int bn0 = (int)(g % gridDim.x) * BN;
  f32x4 acc[MI][4] = {};

  for (int k0 = 0; k0 < K; k0 += 64) {
#pragma unroll
    for (int j = 0; j < 4; ++j) {
      const int cbase = j * 256 + wave * 64;
      const int c = cbase + lane;
      const int row = c >> 3, slot = c & 7;
      GLD16(A + (size_t)(bm0 + row) * K + k0 + ((slot ^ (row & 7)) * 8),
            (char*)As + cbase * 16);
    }
#pragma unroll
    for (int j = 0; j < BN / 32; ++j) {
      const int cbase = j * 256 + wave * 64;
      const int c = cbase + lane;
      const int row = c >> 3, slot = c & 7;
      GLD16(BT + (size_t)(bn0 + row) * K + k0 + ((slot ^ (row & 7)) * 8),
            (char*)Bs + cbase * 16);
    }
    __syncthreads();
#pragma unroll
    for (int kk = 0; kk < 2; ++kk) {
      const int co = (kk * 64 + lq * 16) ^ ((lr & 7) << 4);
      bf16x8 af[MI], bfr[4];
#pragma unroll
      for (int i = 0; i < MI; ++i)
        af[i] = *reinterpret_cast<const bf16x8*>(
            (const char*)As + (wr * (MI * 16) + i * 16 + lr) * 128 + co);
#pragma unroll
      for (int i = 0; i < 4; ++i)
        bfr[i] = *reinterpret_cast<const bf16x8*>(
            (const char*)Bs + (wc * 64 + i * 16 + lr) * 128 + co);
#pragma unroll
      for (int mi = 0; mi < MI; ++mi)
#pragma unroll
        for (int ni = 0; ni < 4; ++ni)
          acc[mi][ni] = __builtin_amdgcn_mfma_f32_16x16x32_bf16(af[mi], bfr[ni], acc[mi][ni], 0, 0, 0);
    }
    __syncthreads();
  }

#pragma unroll
  for (int mi = 0; mi < MI; ++mi) {
#pragma unroll
    for (int ni = 0; ni < 4; ++ni) {
      const int col = bn0 + wc * 64 + ni * 16 + lr;
      const float bv = (EPI >= 1) ? bias[col] : 0.0f;
#pragma unroll
      for (int j = 0; j < 4; ++j) {
        const int row = bm0 + wr * (MI * 16) + mi * 16 + lq * 4 + j;
        float v = acc[mi][ni][j] + bv;
        if (HASRES == 1) v += RESF[(size_t)row * N + col];
        if (HASRES == 2) v += __bfloat162float(RESB[(size_t)row * N + col]);
        if (EPI == 2) v = 0.5f * v * (1.0f + erff(v * 0.70710678118654752f));
        if (OUTB) Cb[(size_t)row * N + col] = __float2bfloat16(v);
        else      Cf[(size_t)row * N + col] = v;
      }
    }
  }
}

// ---------------- causal flash attention v12: 8-way split-K (512 threads) ----------------
// Block: 32 q-rows, 8 waves split-K round-robin (KVBLK=32), no in-loop barriers.
// Inner loop identical to the r13-verified body; heavy-block serial span halved
// (16 -> 8 tiles/wave) and CU wave-capacity maxed (4 blk/CU x 8 waves = 32).

#define DIAG_MASK(sv)                                                               \
  _Pragma("unroll")                                                                 \
  for (int r = 0; r < 16; ++r) {                                                    \
    const int kl = (r & 3) + 8 * (r >> 2) + 4 * hi;                                 \
    if (kl > lq32) sv[r] = -1e30f;                                                  \
  }

#define PV_HALF(wl0, wl1, wh0, wh1, ksg)                                            \
  {                                                                                 \
    unsigned t0_ = hi ? (wl0) : (wh0);                                              \
    unsigned t1_ = hi ? (wl1) : (wh1);                                              \
    t0_ = (unsigned)__shfl_xor((int)t0_, 32);                                       \
    t1_ = (unsigned)__shfl_xor((int)t1_, 32);                                       \
    u32x4 fw;                                                                       \
    fw[0] = hi ? t0_ : (wl0);  fw[1] = hi ? t1_ : (wl1);                            \
    fw[2] = hi ? (wh0) : t0_;  fw[3] = hi ? (wh1) : t1_;                            \
    bf16x8 pfb = __builtin_bit_cast(bf16x8, fw);                                    \
    const int krow_ = (ksg) * 16 + 8 * hi;                                          \
    bf16x8 vA, vB;                                                                  \
    _Pragma("unroll")                                                               \
    for (int j_ = 0; j_ < 8; ++j_) {                                                \
      vA[j_] = VwB[(krow_ + j_) * 64 + lq32];                                       \
      vB[j_] = VwB[(krow_ + j_) * 64 + 32 + lq32];                                  \
    }                                                                               \
    __builtin_amdgcn_s_setprio(1);                                                  \
    o0 = __builtin_amdgcn_mfma_f32_32x32x16_bf16(vA, pfb, o0, 0, 0, 0);             \
    o1 = __builtin_amdgcn_mfma_f32_32x32x16_bf16(vB, pfb, o1, 0, 0, 0);             \
    __builtin_amdgcn_s_setprio(0);                                                  \
  }

__global__ __launch_bounds__(512, 4) void attn_k(const __hip_bfloat16* __restrict__ qkv,
                                                 __hip_bfloat16* __restrict__ outb) {
  __shared__ __align__(16) char smem[8 * 4096 + 4096];
  // XCD-aware swizzle: xcd = bid%8 owns 4 heads; heavy q-blocks dispatched first
  const int bid = blockIdx.x;
  const int seq = bid >> 3;
  const int bh  = (bid & 7) * 4 + (seq & 3);     // 0..31
  const int qt32 = 63 - (seq >> 2);              // 0..63, heavy first
  const int b = bh >> 4, h = bh & 15;
  const int qb = qt32 * 32;
  const int tid = threadIdx.x;
  const int lane = tid & 63, wave = tid >> 6;    // wave 0..7
  const int lq32 = lane & 31, hi = lane >> 5;
  const size_t rowbase = (size_t)(b * L_SEQ) * QKV_LD;
  char* const Vw = smem + wave * 4096;           // wave slice: V rows / bf16 O^T partials
  const __bf16* const VwB = (const __bf16*)Vw;
  float* const ML = (float*)(smem + 32768);      // 8 x 128 floats

  // Q B-frags: lane holds Q[qb+lq32][16c + 8hi + j]
  bf16x8 qf[4];
  {
    const __hip_bfloat16* qp = qkv + rowbase + (size_t)(qb + lq32) * QKV_LD + h * HDIM + 8 * hi;
#pragma unroll
    for (int c = 0; c < 4; ++c) qf[c] = *reinterpret_cast<const bf16x8*>(qp + 16 * c);
  }

  f32x16 o0 = {}, o1 = {};
  float m = -1e30f, lsum = 0.0f;

  int t = wave;
  bf16x8 kr0, kr1, kr2, kr3;
  if (t <= qt32) {                               // prime K regs for first tile
    const __hip_bfloat16* kp = qkv + rowbase + (size_t)(t * 32 + lq32) * QKV_LD + DM + h * HDIM + 8 * hi;
    kr0 = *reinterpret_cast<const bf16x8*>(kp);
    kr1 = *reinterpret_cast<const bf16x8*>(kp + 16);
    kr2 = *reinterpret_cast<const bf16x8*>(kp + 32);
    kr3 = *reinterpret_cast<const bf16x8*>(kp + 48);
  }

  for (; t <= qt32; t += 8) {
    const int k0 = t * 32;
    const bool pf = (t + 8 <= qt32);
    // ---- prefetch next K tile into regs (consumed next iter) ----
    bf16x8 kn0, kn1, kn2, kn3;
    if (pf) {
      const __hip_bfloat16* kp = qkv + rowbase + (size_t)(k0 + 256 + lq32) * QKV_LD + DM + h * HDIM + 8 * hi;
      kn0 = *reinterpret_cast<const bf16x8*>(kp);
      kn1 = *reinterpret_cast<const bf16x8*>(kp + 16);
      kn2 = *reinterpret_cast<const bf16x8*>(kp + 32);
      kn3 = *reinterpret_cast<const bf16x8*>(kp + 48);
    }
    // ---- V rows -> wave-private LDS via async DMA (linear, conflict-free) ----
#pragma unroll
    for (int p = 0; p < 4; ++p)
      GLD16(qkv + rowbase + (size_t)(k0 + 8 * p + (lane >> 3)) * QKV_LD + 2 * DM + h * HDIM + (lane & 7) * 8,
            Vw + p * 1024);
    // ---- QK ----
    f32x16 s = {};
    __builtin_amdgcn_s_setprio(1);
    s = __builtin_amdgcn_mfma_f32_32x32x16_bf16(kr0, qf[0], s, 0, 0, 0);
    s = __builtin_amdgcn_mfma_f32_32x32x16_bf16(kr1, qf[1], s, 0, 0, 0);
    s = __builtin_amdgcn_mfma_f32_32x32x16_bf16(kr2, qf[2], s, 0, 0, 0);
    s = __builtin_amdgcn_mfma_f32_32x32x16_bf16(kr3, qf[3], s, 0, 0, 0);
    __builtin_amdgcn_s_setprio(0);
    if (t == qt32) { DIAG_MASK(s) }
    // ---- online softmax (tree max, defer-rescale THR) ----
    float a0 = fmaxf(s[0], s[1]),   a1 = fmaxf(s[2], s[3]);
    float a2 = fmaxf(s[4], s[5]),   a3 = fmaxf(s[6], s[7]);
    float a4 = fmaxf(s[8], s[9]),   a5 = fmaxf(s[10], s[11]);
    float a6 = fmaxf(s[12], s[13]), a7 = fmaxf(s[14], s[15]);
    a0 = fmaxf(a0, a1); a2 = fmaxf(a2, a3); a4 = fmaxf(a4, a5); a6 = fmaxf(a6, a7);
    float tm = fmaxf(fmaxf(a0, a2), fmaxf(a4, a6));
    tm = fmaxf(tm, __shfl_xor(tm, 32));
    if (!__all(tm <= m + DTHR)) {
      const float mn = fmaxf(m, tm);
      const float fac = __builtin_amdgcn_exp2f((m - mn) * RL);
      m = mn; lsum *= fac; o0 *= fac; o1 *= fac;
    }
    const float mneg = -m * RL;
    float rs = 0.0f;
#pragma unroll
    for (int r = 0; r < 16; ++r) {
      s[r] = __builtin_amdgcn_exp2f(fmaf(s[r], RL, mneg));
      rs += s[r];
    }
    rs += __shfl_xor(rs, 32);
    lsum += rs;
    // ---- PV ----
    unsigned w0 = pack2(s[0], s[1]),   w1 = pack2(s[2], s[3]);
    unsigned w2 = pack2(s[4], s[5]),   w3 = pack2(s[6], s[7]);
    unsigned w4 = pack2(s[8], s[9]),   w5 = pack2(s[10], s[11]);
    unsigned w6 = pack2(s[12], s[13]), w7 = pack2(s[14], s[15]);
    PV_HALF(w0, w1, w2, w3, 0)
    PV_HALF(w4, w5, w6, w7, 1)
    if (pf) { kr0 = kn0; kr1 = kn1; kr2 = kn2; kr3 = kn3; }
  }

  // ---- write partials (bf16 O^T into own slice; m,l) ----
  {
    __bf16* Ow = (__bf16*)Vw;
#pragma unroll
    for (int r = 0; r < 16; ++r) {
      const int d0 = (r & 3) + 8 * (r >> 2) + 4 * hi;
      Ow[d0 * 32 + lq32] = (__bf16)o0[r];
      Ow[(d0 + 32) * 32 + lq32] = (__bf16)o1[r];
    }
    if (hi == 0) {
      ML[wave * 128 + lq32] = m;
      ML[wave * 128 + 64 + lq32] = lsum;
    }
  }
  __syncthreads();

  // ---- combine 8 partials; each thread: one q (tid&31), 4 d's ----
  {
    const int q = tid & 31, dgr = tid >> 5;      // dgr 0..15, d = dgr*4 + i
    float mw[8], cw[8];
    float M = -1e30f;
#pragma unroll
    for (int w = 0; w < 8; ++w) { mw[w] = ML[w * 128 + q]; M = fmaxf(M, mw[w]); }
    float l = 0.0f;
#pragma unroll
    for (int w = 0; w < 8; ++w) {
      cw[w] = __builtin_amdgcn_exp2f((mw[w] - M) * RL);
      l += cw[w] * ML[w * 128 + 64 + q];
    }
    const float inv = 1.0f / l;
    const __bf16* OB = (const __bf16*)smem;
    bf16x4 ov;
#pragma unroll
    for (int i = 0; i < 4; ++i) {
      const int idx = (dgr * 4 + i) * 32 + q;
      float v = 0.0f;
#pragma unroll
      for (int w = 0; w < 8; ++w)
        v += cw[w] * (float)OB[w * 2048 + idx];
      ov[i] = (__bf16)(v * inv);
    }
    *reinterpret_cast<bf16x4*>(outb + (size_t)(b * L_SEQ + qb + q) * DM + h * HDIM + dgr * 4) = ov;
  }
}

// ---------------- LayerNorm: Y = LN(X) * g + be. INB: bf16 input. OUTB2: bf16 out ----
template<int INB, int OUTB2>
__global__ __launch_bounds__(256) void ln_k(const void* __restrict__ Xv,
                                            const float* __restrict__ g,
                                            const float* __restrict__ be,
                                            float* __restrict__ Y,
                                            __hip_bfloat16* __restrict__ Yb) {
  const int row = blockIdx.x;
  const int tid = threadIdx.x;
  const int lane = tid & 63, wave = tid >> 6;
  float v0, v1, v2, v3;
  if (INB) {
    const __bf16* X = (const __bf16*)Xv;
    bf16x4 x4 = *reinterpret_cast<const bf16x4*>(X + (size_t)row * DM + tid * 4);
    v0 = (float)x4[0]; v1 = (float)x4[1]; v2 = (float)x4[2]; v3 = (float)x4[3];
  } else {
    const float* X = (const float*)Xv;
    float4 x4 = *reinterpret_cast<const float4*>(X + (size_t)row * DM + tid * 4);
    v0 = x4.x; v1 = x4.y; v2 = x4.z; v3 = x4.w;
  }
  float s  = v0 + v1 + v2 + v3;
  float ss = v0 * v0 + v1 * v1 + v2 * v2 + v3 * v3;
#pragma unroll
  for (int off = 1; off < 64; off <<= 1) {
    s  += __shfl_xor(s, off);
    ss += __shfl_xor(ss, off);
  }
  __shared__ float red[8];
  if (lane == 0) { red[wave] = s; red[4 + wave] = ss; }
  __syncthreads();
  float S  = red[0] + red[1] + red[2] + red[3];
  float SS = red[4] + red[5] + red[6] + red[7];
  float mu  = S * (1.0f / DM);
  float var = SS * (1.0f / DM) - mu * mu;
  float rsd = rsqrtf(var + 1e-5f);
  float4 gv = *reinterpret_cast<const float4*>(g + tid * 4);
  float4 bv = *reinterpret_cast<const float4*>(be + tid * 4);
  float4 y;
  y.x = (v0 - mu) * rsd * gv.x + bv.x;
  y.y = (v1 - mu) * rsd * gv.y + bv.y;
  y.z = (v2 - mu) * rsd * gv.z + bv.z;
  y.w = (v3 - mu) * rsd * gv.w + bv.w;
  if (OUTB2) {
    bf16x4 yb;
    yb[0] = (__bf16)y.x; yb[1] = (__bf16)y.y; yb[2] = (__bf16)y.z; yb[3] = (__bf16)y.w;
    *reinterpret_cast<bf16x4*>(Yb + (size_t)row * DM + tid * 4) = yb;
  } else {
    *reinterpret_cast<float4*>(Y + (size_t)row * DM + tid * 4) = y;
  }
}

extern "C" void kernel_launch(void* const* d_in, const int* in_sizes, int n_in,
                              void* d_out, int out_size, void* d_ws, size_t ws_size,
                              hipStream_t stream) {
  const float* x     = (const float*)d_in[0];
  const float* w_qkv = (const float*)d_in[1];
  const float* w_out = (const float*)d_in[2];
  const float* w1    = (const float*)d_in[3];
  const float* b1    = (const float*)d_in[4];
  const float* w2    = (const float*)d_in[5];
  const float* b2    = (const float*)d_in[6];
  const float* g1    = (const float*)d_in[7];
  const float* be1   = (const float*)d_in[8];
  const float* g2    = (const float*)d_in[9];
  const float* be2   = (const float*)d_in[10];
  float* outp = (float*)d_out;
  char* base  = (char*)d_ws;
  const int M = NB * L_SEQ;                 // 4096

  // workspace layout (MiB): [0,4)w2T [4,6)woT [6,10)w1T [10,16)wqT [16,24)xb
  // [24,48)qkvb -> [24,40)ffh after qkv dead; [40,48)ln1b; [48,56)projb;
  // [56,64)attnb; [8,16)ffob (w1T/wqT dead by step 6). All lifetimes traced.
  __hip_bfloat16* w2T  = (__hip_bfloat16*)(base + 0);
  __hip_bfloat16* woT  = (__hip_bfloat16*)(base + 4194304);
  __hip_bfloat16* w1T  = (__hip_bfloat16*)(base + 6291456);
  __hip_bfloat16* wqT  = (__hip_bfloat16*)(base + 10485760);
  __hip_bfloat16* xb   = (__hip_bfloat16*)(base + 16777216);
  __hip_bfloat16* qkvb = (__hip_bfloat16*)(base + 25165824);
  __hip_bfloat16* ffh  = (__hip_bfloat16*)(base + 25165824);
  __hip_bfloat16* ln1b = (__hip_bfloat16*)(base + 41943040);
  __hip_bfloat16* projb= (__hip_bfloat16*)(base + 50331648);
  __hip_bfloat16* attnb= (__hip_bfloat16*)(base + 58720256);
  __hip_bfloat16* ffob = (__hip_bfloat16*)(base + 8388608);

  // fused prep: all weight transposes + x convert
  prep_k<<<10240, 256, 0, stream>>>(w_qkv, w_out, w1, w2, x, wqT, woT, w1T, w2T, xb);

  // 1. qkv = x @ w_qkv (bf16)
  gemm2<0, 1, 0, 128><<<dim3(24, 32), 256, 0, stream>>>(xb, wqT, nullptr, nullptr, qkvb, nullptr, nullptr, M, QKV_LD, DM);
  // 2. attention (bf16): 64 q-blocks x 32 bh, XCD-swizzled, 8-way split-K
  attn_k<<<2048, 512, 0, stream>>>(qkvb, attnb);
  // 3. proj = attn @ w_out + x  (bf16 out, bf16 residual; BN=64)
  gemm2<0, 1, 2, 64><<<dim3(16, 32), 256, 0, stream>>>(attnb, woT, nullptr, nullptr, projb, nullptr, xb, M, DM, DM);
  // 4. ln1 = LN(proj)  (bf16 in, bf16 out)
  ln_k<1, 1><<<M, 256, 0, stream>>>(projb, g1, be1, nullptr, ln1b);
  // 5. ffh = gelu(ln1 @ w1 + b1) (bf16)
  gemm2<2, 1, 0, 128><<<dim3(16, 32), 256, 0, stream>>>(ln1b, w1T, b1, nullptr, ffh, nullptr, nullptr, M, 2 * DM, DM);
  // 6. ffo = ffh @ w2 + b2 + ln1 (bf16 out, bf16 residual; BN=64)
  gemm2<1, 1, 2, 64><<<dim3(16, 32), 256, 0, stream>>>(ffh, w2T, b2, nullptr, ffob, nullptr, ln1b, M, DM, 2 * DM);
  // 7. out = LN(ffo)  (bf16 in, f32 out)
  ln_k<1, 0><<<M, 256, 0, stream>>>(ffob, g2, be2, outp, nullptr);
}

// Round 16
// 191.624 us; speedup vs baseline: 1.0244x; 1.0244x over previous
//
#include <hip/hip_runtime.h>
#include <hip/hip_bf16.h>
#include <math.h>

#define L_SEQ 2048
#define NB 2
#define DM 1024
#define NHEAD 16
#define HDIM 64
#define QKV_LD 3072
#define RL 0.18033688011112042f   // 0.125 * log2(e)
#define DTHR 44.3614f             // 8 / RL  (defer-max threshold in raw score units)

typedef __attribute__((ext_vector_type(8))) __bf16 bf16x8;
typedef __attribute__((ext_vector_type(4))) __bf16 bf16x4;
typedef __attribute__((ext_vector_type(4))) float f32x4;
typedef __attribute__((ext_vector_type(16))) float f32x16;
typedef __attribute__((ext_vector_type(4))) unsigned int u32x4;

typedef __attribute__((address_space(3))) unsigned int lds_u32;
typedef const __attribute__((address_space(1))) unsigned int glob_u32;
#define GLD16(g, l) __builtin_amdgcn_global_load_lds((glob_u32*)(g), (lds_u32*)(l), 16, 0, 0)

__device__ __forceinline__ unsigned pack2(float a, float b) {
  unsigned short ua = __builtin_bit_cast(unsigned short, (__bf16)a);
  unsigned short ub = __builtin_bit_cast(unsigned short, (__bf16)b);
  return (unsigned)ua | ((unsigned)ub << 16);
}

// ---------------- fused prep: 4 weight transposes + x convert ----------------
__global__ __launch_bounds__(256) void prep_k(const float* __restrict__ w_qkv,
                                              const float* __restrict__ w_out,
                                              const float* __restrict__ w1,
                                              const float* __restrict__ w2,
                                              const float* __restrict__ x,
                                              __hip_bfloat16* __restrict__ wqT,
                                              __hip_bfloat16* __restrict__ woT,
                                              __hip_bfloat16* __restrict__ w1T,
                                              __hip_bfloat16* __restrict__ w2T,
                                              __hip_bfloat16* __restrict__ xb) {
  const int id = blockIdx.x;
  if (id >= 8192) {                     // x f32 -> bf16
    const size_t base = ((size_t)(id - 8192) * 256 + threadIdx.x) * 8;
    float4 a = *reinterpret_cast<const float4*>(x + base);
    float4 b = *reinterpret_cast<const float4*>(x + base + 4);
    bf16x8 o;
    o[0] = (__bf16)a.x; o[1] = (__bf16)a.y; o[2] = (__bf16)a.z; o[3] = (__bf16)a.w;
    o[4] = (__bf16)b.x; o[5] = (__bf16)b.y; o[6] = (__bf16)b.z; o[7] = (__bf16)b.w;
    *reinterpret_cast<bf16x8*>(xb + base) = o;
    return;
  }
  const float* W; __hip_bfloat16* WT; int K, N, kb, nb;
  if (id < 3072)      { W = w_qkv; WT = wqT; K = 1024; N = 3072; kb = id & 31;          nb = id >> 5; }
  else if (id < 4096) { W = w_out; WT = woT; K = 1024; N = 1024; kb = (id - 3072) & 31; nb = (id - 3072) >> 5; }
  else if (id < 6144) { W = w1;    WT = w1T; K = 1024; N = 2048; kb = (id - 4096) & 31; nb = (id - 4096) >> 5; }
  else                { W = w2;    WT = w2T; K = 2048; N = 1024; kb = (id - 6144) & 63; nb = (id - 6144) >> 6; }
  __shared__ float tsm[32][33];
  const int k0 = kb * 32, n0 = nb * 32;
  const int c = threadIdx.x & 31, r = threadIdx.x >> 5;
#pragma unroll
  for (int i = 0; i < 4; ++i)
    tsm[r + 8 * i][c] = W[(size_t)(k0 + r + 8 * i) * N + n0 + c];
  __syncthreads();
#pragma unroll
  for (int i = 0; i < 4; ++i)
    WT[(size_t)(n0 + r + 8 * i) * K + k0 + c] = __float2bfloat16(tsm[c][r + 8 * i]);
}

// ---------------- GEMM v2: BK=64, both-sides XOR swizzle, XCD block swizzle ----------------
template<int EPI, int OUTB, int HASRES, int BN>
__global__ __launch_bounds__(256) void gemm2(const __hip_bfloat16* __restrict__ A,
                                             const __hip_bfloat16* __restrict__ BT,
                                             const float* __restrict__ bias,
                                             float* __restrict__ Cf,
                                             __hip_bfloat16* __restrict__ Cb,
                                             const float* __restrict__ RESF,
                                             const __hip_bfloat16* __restrict__ RESB,
                                             int M, int N, int K) {
  constexpr int MI = (BN == 128) ? 4 : 2;
  __shared__ __align__(16) __hip_bfloat16 As[128 * 64];
  __shared__ __align__(16) __hip_bfloat16 Bs[BN * 64];
  const int tid  = threadIdx.x;
  const int lane = tid & 63, wave = tid >> 6;
  const int wr = (BN == 128) ? (wave >> 1) : wave;
  const int wc = (BN == 128) ? (wave & 1) : 0;
  const int lr = lane & 15, lq = lane >> 4;
  unsigned g = blockIdx.y * gridDim.x + blockIdx.x;
  const unsigned cpx = (gridDim.x * gridDim.y) >> 3;
  g = (g & 7) * cpx + (g >> 3);
  const int bm0 = (int)(g / gridDim.x) * 128;
  const int bn0 = (int)(g % gridDim.x) * BN;
  f32x4 acc[MI][4] = {};

  for (int k0 = 0; k0 < K; k0 += 64) {
#pragma unroll
    for (int j = 0; j < 4; ++j) {
      const int cbase = j * 256 + wave * 64;
      const int c = cbase + lane;
      const int row = c >> 3, slot = c & 7;
      GLD16(A + (size_t)(bm0 + row) * K + k0 + ((slot ^ (row & 7)) * 8),
            (char*)As + cbase * 16);
    }
#pragma unroll
    for (int j = 0; j < BN / 32; ++j) {
      const int cbase = j * 256 + wave * 64;
      const int c = cbase + lane;
      const int row = c >> 3, slot = c & 7;
      GLD16(BT + (size_t)(bn0 + row) * K + k0 + ((slot ^ (row & 7)) * 8),
            (char*)Bs + cbase * 16);
    }
    __syncthreads();
#pragma unroll
    for (int kk = 0; kk < 2; ++kk) {
      const int co = (kk * 64 + lq * 16) ^ ((lr & 7) << 4);
      bf16x8 af[MI], bfr[4];
#pragma unroll
      for (int i = 0; i < MI; ++i)
        af[i] = *reinterpret_cast<const bf16x8*>(
            (const char*)As + (wr * (MI * 16) + i * 16 + lr) * 128 + co);
#pragma unroll
      for (int i = 0; i < 4; ++i)
        bfr[i] = *reinterpret_cast<const bf16x8*>(
            (const char*)Bs + (wc * 64 + i * 16 + lr) * 128 + co);
#pragma unroll
      for (int mi = 0; mi < MI; ++mi)
#pragma unroll
        for (int ni = 0; ni < 4; ++ni)
          acc[mi][ni] = __builtin_amdgcn_mfma_f32_16x16x32_bf16(af[mi], bfr[ni], acc[mi][ni], 0, 0, 0);
    }
    __syncthreads();
  }

#pragma unroll
  for (int mi = 0; mi < MI; ++mi) {
#pragma unroll
    for (int ni = 0; ni < 4; ++ni) {
      const int col = bn0 + wc * 64 + ni * 16 + lr;
      const float bv = (EPI >= 1) ? bias[col] : 0.0f;
#pragma unroll
      for (int j = 0; j < 4; ++j) {
        const int row = bm0 + wr * (MI * 16) + mi * 16 + lq * 4 + j;
        float v = acc[mi][ni][j] + bv;
        if (HASRES == 1) v += RESF[(size_t)row * N + col];
        if (HASRES == 2) v += __bfloat162float(RESB[(size_t)row * N + col]);
        if (EPI == 2) v = 0.5f * v * (1.0f + erff(v * 0.70710678118654752f));
        if (OUTB) Cb[(size_t)row * N + col] = __float2bfloat16(v);
        else      Cf[(size_t)row * N + col] = v;
      }
    }
  }
}

// ---------------- causal flash attention (r11/r13-verified floor) ----------------
// Block: 32 q-rows, 4 waves split-K round-robin (KVBLK=32), no in-loop barriers.
// Swapped QK (lane owns one q-row); K prefetched in regs one tile ahead;
// V staged ROW-major per wave via global_load_lds (async DMA, conflict-free);
// PV A-frags via scalar ds_read_u16 (2-way, free); bf16 O^T partials; combine.

#define DIAG_MASK(sv)                                                               \
  _Pragma("unroll")                                                                 \
  for (int r = 0; r < 16; ++r) {                                                    \
    const int kl = (r & 3) + 8 * (r >> 2) + 4 * hi;                                 \
    if (kl > lq32) sv[r] = -1e30f;                                                  \
  }

#define PV_HALF(wl0, wl1, wh0, wh1, ksg)                                            \
  {                                                                                 \
    unsigned t0_ = hi ? (wl0) : (wh0);                                              \
    unsigned t1_ = hi ? (wl1) : (wh1);                                              \
    t0_ = (unsigned)__shfl_xor((int)t0_, 32);                                       \
    t1_ = (unsigned)__shfl_xor((int)t1_, 32);                                       \
    u32x4 fw;                                                                       \
    fw[0] = hi ? t0_ : (wl0);  fw[1] = hi ? t1_ : (wl1);                            \
    fw[2] = hi ? (wh0) : t0_;  fw[3] = hi ? (wh1) : t1_;                            \
    bf16x8 pfb = __builtin_bit_cast(bf16x8, fw);                                    \
    const int krow_ = (ksg) * 16 + 8 * hi;                                          \
    bf16x8 vA, vB;                                                                  \
    _Pragma("unroll")                                                               \
    for (int j_ = 0; j_ < 8; ++j_) {                                                \
      vA[j_] = VwB[(krow_ + j_) * 64 + lq32];                                       \
      vB[j_] = VwB[(krow_ + j_) * 64 + 32 + lq32];                                  \
    }                                                                               \
    __builtin_amdgcn_s_setprio(1);                                                  \
    o0 = __builtin_amdgcn_mfma_f32_32x32x16_bf16(vA, pfb, o0, 0, 0, 0);             \
    o1 = __builtin_amdgcn_mfma_f32_32x32x16_bf16(vB, pfb, o1, 0, 0, 0);             \
    __builtin_amdgcn_s_setprio(0);                                                  \
  }

__global__ __launch_bounds__(256, 4) void attn_k(const __hip_bfloat16* __restrict__ qkv,
                                                 __hip_bfloat16* __restrict__ outb) {
  __shared__ __align__(16) char smem[4 * 4096 + 2048];
  // XCD-aware swizzle: xcd = bid%8 owns 4 heads; heavy q-blocks dispatched first
  const int bid = blockIdx.x;
  const int seq = bid >> 3;
  const int bh  = (bid & 7) * 4 + (seq & 3);     // 0..31
  const int qt32 = 63 - (seq >> 2);              // 0..63, heavy first
  const int b = bh >> 4, h = bh & 15;
  const int qb = qt32 * 32;
  const int tid = threadIdx.x;
  const int lane = tid & 63, wave = tid >> 6;
  const int lq32 = lane & 31, hi = lane >> 5;
  const size_t rowbase = (size_t)(b * L_SEQ) * QKV_LD;
  char* const Vw = smem + wave * 4096;           // wave slice: V rows / bf16 O^T partials
  const __bf16* const VwB = (const __bf16*)Vw;
  float* const ML = (float*)(smem + 16384);

  // Q B-frags: lane holds Q[qb+lq32][16c + 8hi + j]
  bf16x8 qf[4];
  {
    const __hip_bfloat16* qp = qkv + rowbase + (size_t)(qb + lq32) * QKV_LD + h * HDIM + 8 * hi;
#pragma unroll
    for (int c = 0; c < 4; ++c) qf[c] = *reinterpret_cast<const bf16x8*>(qp + 16 * c);
  }

  f32x16 o0 = {}, o1 = {};
  float m = -1e30f, lsum = 0.0f;

  int t = wave;
  bf16x8 kr0, kr1, kr2, kr3;
  if (t <= qt32) {                               // prime K regs for first tile
    const __hip_bfloat16* kp = qkv + rowbase + (size_t)(t * 32 + lq32) * QKV_LD + DM + h * HDIM + 8 * hi;
    kr0 = *reinterpret_cast<const bf16x8*>(kp);
    kr1 = *reinterpret_cast<const bf16x8*>(kp + 16);
    kr2 = *reinterpret_cast<const bf16x8*>(kp + 32);
    kr3 = *reinterpret_cast<const bf16x8*>(kp + 48);
  }

  for (; t <= qt32; t += 4) {
    const int k0 = t * 32;
    const bool pf = (t + 4 <= qt32);
    // ---- prefetch next K tile into regs (consumed next iter) ----
    bf16x8 kn0, kn1, kn2, kn3;
    if (pf) {
      const __hip_bfloat16* kp = qkv + rowbase + (size_t)(k0 + 128 + lq32) * QKV_LD + DM + h * HDIM + 8 * hi;
      kn0 = *reinterpret_cast<const bf16x8*>(kp);
      kn1 = *reinterpret_cast<const bf16x8*>(kp + 16);
      kn2 = *reinterpret_cast<const bf16x8*>(kp + 32);
      kn3 = *reinterpret_cast<const bf16x8*>(kp + 48);
    }
    // ---- V rows -> wave-private LDS via async DMA (linear, conflict-free) ----
#pragma unroll
    for (int p = 0; p < 4; ++p)
      GLD16(qkv + rowbase + (size_t)(k0 + 8 * p + (lane >> 3)) * QKV_LD + 2 * DM + h * HDIM + (lane & 7) * 8,
            Vw + p * 1024);
    // ---- QK ----
    f32x16 s = {};
    __builtin_amdgcn_s_setprio(1);
    s = __builtin_amdgcn_mfma_f32_32x32x16_bf16(kr0, qf[0], s, 0, 0, 0);
    s = __builtin_amdgcn_mfma_f32_32x32x16_bf16(kr1, qf[1], s, 0, 0, 0);
    s = __builtin_amdgcn_mfma_f32_32x32x16_bf16(kr2, qf[2], s, 0, 0, 0);
    s = __builtin_amdgcn_mfma_f32_32x32x16_bf16(kr3, qf[3], s, 0, 0, 0);
    __builtin_amdgcn_s_setprio(0);
    if (t == qt32) { DIAG_MASK(s) }
    // ---- online softmax (tree max, defer-rescale THR) ----
    float a0 = fmaxf(s[0], s[1]),   a1 = fmaxf(s[2], s[3]);
    float a2 = fmaxf(s[4], s[5]),   a3 = fmaxf(s[6], s[7]);
    float a4 = fmaxf(s[8], s[9]),   a5 = fmaxf(s[10], s[11]);
    float a6 = fmaxf(s[12], s[13]), a7 = fmaxf(s[14], s[15]);
    a0 = fmaxf(a0, a1); a2 = fmaxf(a2, a3); a4 = fmaxf(a4, a5); a6 = fmaxf(a6, a7);
    float tm = fmaxf(fmaxf(a0, a2), fmaxf(a4, a6));
    tm = fmaxf(tm, __shfl_xor(tm, 32));
    if (!__all(tm <= m + DTHR)) {
      const float mn = fmaxf(m, tm);
      const float fac = __builtin_amdgcn_exp2f((m - mn) * RL);
      m = mn; lsum *= fac; o0 *= fac; o1 *= fac;
    }
    const float mneg = -m * RL;
    float rs = 0.0f;
#pragma unroll
    for (int r = 0; r < 16; ++r) {
      s[r] = __builtin_amdgcn_exp2f(fmaf(s[r], RL, mneg));
      rs += s[r];
    }
    rs += __shfl_xor(rs, 32);
    lsum += rs;
    // ---- PV ----
    unsigned w0 = pack2(s[0], s[1]),   w1 = pack2(s[2], s[3]);
    unsigned w2 = pack2(s[4], s[5]),   w3 = pack2(s[6], s[7]);
    unsigned w4 = pack2(s[8], s[9]),   w5 = pack2(s[10], s[11]);
    unsigned w6 = pack2(s[12], s[13]), w7 = pack2(s[14], s[15]);
    PV_HALF(w0, w1, w2, w3, 0)
    PV_HALF(w4, w5, w6, w7, 1)
    if (pf) { kr0 = kn0; kr1 = kn1; kr2 = kn2; kr3 = kn3; }
  }

  // ---- write partials (bf16 O^T into own slice; m,l) ----
  {
    __bf16* Ow = (__bf16*)Vw;
#pragma unroll
    for (int r = 0; r < 16; ++r) {
      const int d0 = (r & 3) + 8 * (r >> 2) + 4 * hi;
      Ow[d0 * 32 + lq32] = (__bf16)o0[r];
      Ow[(d0 + 32) * 32 + lq32] = (__bf16)o1[r];
    }
    if (hi == 0) {
      ML[wave * 128 + lq32] = m;
      ML[wave * 128 + 64 + lq32] = lsum;
    }
  }
  __syncthreads();

  // ---- combine 4 partials; each thread: one q (tid&31), 8 d's ----
  {
    const int q = tid & 31, dg = tid >> 5;    // dg 0..7
    const float m0 = ML[q], m1 = ML[128 + q], m2 = ML[256 + q], m3 = ML[384 + q];
    const float M = fmaxf(fmaxf(m0, m1), fmaxf(m2, m3));
    const float c0 = __builtin_amdgcn_exp2f((m0 - M) * RL);
    const float c1 = __builtin_amdgcn_exp2f((m1 - M) * RL);
    const float c2 = __builtin_amdgcn_exp2f((m2 - M) * RL);
    const float c3 = __builtin_amdgcn_exp2f((m3 - M) * RL);
    const float l = c0 * ML[64 + q] + c1 * ML[192 + q] + c2 * ML[320 + q] + c3 * ML[448 + q];
    const float inv = 1.0f / l;
    const __bf16* OB = (const __bf16*)smem;
    bf16x8 ov;
#pragma unroll
    for (int i = 0; i < 8; ++i) {
      const int idx = (dg * 8 + i) * 32 + q;
      const float v = c0 * (float)OB[idx] + c1 * (float)OB[2048 + idx]
                    + c2 * (float)OB[4096 + idx] + c3 * (float)OB[6144 + idx];
      ov[i] = (__bf16)(v * inv);
    }
    *reinterpret_cast<bf16x8*>(outb + (size_t)(b * L_SEQ + qb + q) * DM + h * HDIM + dg * 8) = ov;
  }
}

// ---------------- LayerNorm: Y = LN(X) * g + be. INB: bf16 input. OUTB2: bf16 out ----
template<int INB, int OUTB2>
__global__ __launch_bounds__(256) void ln_k(const void* __restrict__ Xv,
                                            const float* __restrict__ g,
                                            const float* __restrict__ be,
                                            float* __restrict__ Y,
                                            __hip_bfloat16* __restrict__ Yb) {
  const int row = blockIdx.x;
  const int tid = threadIdx.x;
  const int lane = tid & 63, wave = tid >> 6;
  float v0, v1, v2, v3;
  if (INB) {
    const __bf16* X = (const __bf16*)Xv;
    bf16x4 x4 = *reinterpret_cast<const bf16x4*>(X + (size_t)row * DM + tid * 4);
    v0 = (float)x4[0]; v1 = (float)x4[1]; v2 = (float)x4[2]; v3 = (float)x4[3];
  } else {
    const float* X = (const float*)Xv;
    float4 x4 = *reinterpret_cast<const float4*>(X + (size_t)row * DM + tid * 4);
    v0 = x4.x; v1 = x4.y; v2 = x4.z; v3 = x4.w;
  }
  float s  = v0 + v1 + v2 + v3;
  float ss = v0 * v0 + v1 * v1 + v2 * v2 + v3 * v3;
#pragma unroll
  for (int off = 1; off < 64; off <<= 1) {
    s  += __shfl_xor(s, off);
    ss += __shfl_xor(ss, off);
  }
  __shared__ float red[8];
  if (lane == 0) { red[wave] = s; red[4 + wave] = ss; }
  __syncthreads();
  float S  = red[0] + red[1] + red[2] + red[3];
  float SS = red[4] + red[5] + red[6] + red[7];
  float mu  = S * (1.0f / DM);
  float var = SS * (1.0f / DM) - mu * mu;
  float rsd = rsqrtf(var + 1e-5f);
  float4 gv = *reinterpret_cast<const float4*>(g + tid * 4);
  float4 bv = *reinterpret_cast<const float4*>(be + tid * 4);
  float4 y;
  y.x = (v0 - mu) * rsd * gv.x + bv.x;
  y.y = (v1 - mu) * rsd * gv.y + bv.y;
  y.z = (v2 - mu) * rsd * gv.z + bv.z;
  y.w = (v3 - mu) * rsd * gv.w + bv.w;
  if (OUTB2) {
    bf16x4 yb;
    yb[0] = (__bf16)y.x; yb[1] = (__bf16)y.y; yb[2] = (__bf16)y.z; yb[3] = (__bf16)y.w;
    *reinterpret_cast<bf16x4*>(Yb + (size_t)row * DM + tid * 4) = yb;
  } else {
    *reinterpret_cast<float4*>(Y + (size_t)row * DM + tid * 4) = y;
  }
}

extern "C" void kernel_launch(void* const* d_in, const int* in_sizes, int n_in,
                              void* d_out, int out_size, void* d_ws, size_t ws_size,
                              hipStream_t stream) {
  const float* x     = (const float*)d_in[0];
  const float* w_qkv = (const float*)d_in[1];
  const float* w_out = (const float*)d_in[2];
  const float* w1    = (const float*)d_in[3];
  const float* b1    = (const float*)d_in[4];
  const float* w2    = (const float*)d_in[5];
  const float* b2    = (const float*)d_in[6];
  const float* g1    = (const float*)d_in[7];
  const float* be1   = (const float*)d_in[8];
  const float* g2    = (const float*)d_in[9];
  const float* be2   = (const float*)d_in[10];
  float* outp = (float*)d_out;
  char* base  = (char*)d_ws;
  const int M = NB * L_SEQ;                 // 4096

  // workspace layout (MiB): [0,4)w2T [4,6)woT [6,10)w1T [10,16)wqT [16,24)xb
  // [24,48)qkvb -> [24,40)ffh after qkv dead; [40,48)ln1b; [48,56)projb;
  // [56,64)attnb; [8,16)ffob (w1T/wqT dead by step 6). All lifetimes traced.
  __hip_bfloat16* w2T  = (__hip_bfloat16*)(base + 0);
  __hip_bfloat16* woT  = (__hip_bfloat16*)(base + 4194304);
  __hip_bfloat16* w1T  = (__hip_bfloat16*)(base + 6291456);
  __hip_bfloat16* wqT  = (__hip_bfloat16*)(base + 10485760);
  __hip_bfloat16* xb   = (__hip_bfloat16*)(base + 16777216);
  __hip_bfloat16* qkvb = (__hip_bfloat16*)(base + 25165824);
  __hip_bfloat16* ffh  = (__hip_bfloat16*)(base + 25165824);
  __hip_bfloat16* ln1b = (__hip_bfloat16*)(base + 41943040);
  __hip_bfloat16* projb= (__hip_bfloat16*)(base + 50331648);
  __hip_bfloat16* attnb= (__hip_bfloat16*)(base + 58720256);
  __hip_bfloat16* ffob = (__hip_bfloat16*)(base + 8388608);

  // fused prep: all weight transposes + x convert
  prep_k<<<10240, 256, 0, stream>>>(w_qkv, w_out, w1, w2, x, wqT, woT, w1T, w2T, xb);

  // 1. qkv = x @ w_qkv (bf16)
  gemm2<0, 1, 0, 128><<<dim3(24, 32), 256, 0, stream>>>(xb, wqT, nullptr, nullptr, qkvb, nullptr, nullptr, M, QKV_LD, DM);
  // 2. attention (bf16): 64 q-blocks x 32 bh, XCD-swizzled (r11-verified)
  attn_k<<<2048, 256, 0, stream>>>(qkvb, attnb);
  // 3. proj = attn @ w_out + x  (bf16 out, bf16 residual; BN=64)
  gemm2<0, 1, 2, 64><<<dim3(16, 32), 256, 0, stream>>>(attnb, woT, nullptr, nullptr, projb, nullptr, xb, M, DM, DM);
  // 4. ln1 = LN(proj)  (bf16 in, bf16 out)
  ln_k<1, 1><<<M, 256, 0, stream>>>(projb, g1, be1, nullptr, ln1b);
  // 5. ffh = gelu(ln1 @ w1 + b1) (bf16)
  gemm2<2, 1, 0, 128><<<dim3(16, 32), 256, 0, stream>>>(ln1b, w1T, b1, nullptr, ffh, nullptr, nullptr, M, 2 * DM, DM);
  // 6. ffo = ffh @ w2 + b2 + ln1 (bf16 out, bf16 residual; BN=64)
  gemm2<1, 1, 2, 64><<<dim3(16, 32), 256, 0, stream>>>(ffh, w2T, b2, nullptr, ffob, nullptr, ln1b, M, DM, 2 * DM);
  // 7. out = LN(ffo)  (bf16 in, f32 out)
  ln_k<1, 0><<<M, 256, 0, stream>>>(ffob, g2, be2, outp, nullptr);
}

// Round 18
// 185.876 us; speedup vs baseline: 1.0560x; 1.0309x over previous
//
#include <hip/hip_runtime.h>
#include <hip/hip_bf16.h>
#include <math.h>

#define L_SEQ 2048
#define NB 2
#define DM 1024
#define NHEAD 16
#define HDIM 64
#define QKV_LD 3072
#define RL 0.18033688011112042f   // 0.125 * log2(e)
#define DTHR 44.3614f             // 8 / RL  (defer-max threshold in raw score units)

typedef __attribute__((ext_vector_type(8))) __bf16 bf16x8;
typedef __attribute__((ext_vector_type(4))) __bf16 bf16x4;
typedef __attribute__((ext_vector_type(4))) float f32x4;
typedef __attribute__((ext_vector_type(16))) float f32x16;
typedef __attribute__((ext_vector_type(4))) unsigned int u32x4;

typedef __attribute__((address_space(3))) unsigned int lds_u32;
typedef const __attribute__((address_space(1))) unsigned int glob_u32;
#define GLD16(g, l) __builtin_amdgcn_global_load_lds((glob_u32*)(g), (lds_u32*)(l), 16, 0, 0)

__device__ __forceinline__ unsigned pack2(float a, float b) {
  unsigned short ua = __builtin_bit_cast(unsigned short, (__bf16)a);
  unsigned short ub = __builtin_bit_cast(unsigned short, (__bf16)b);
  return (unsigned)ua | ((unsigned)ub << 16);
}

// ---------------- fused prep: 4 weight transposes + x convert ----------------
__global__ __launch_bounds__(256) void prep_k(const float* __restrict__ w_qkv,
                                              const float* __restrict__ w_out,
                                              const float* __restrict__ w1,
                                              const float* __restrict__ w2,
                                              const float* __restrict__ x,
                                              __hip_bfloat16* __restrict__ wqT,
                                              __hip_bfloat16* __restrict__ woT,
                                              __hip_bfloat16* __restrict__ w1T,
                                              __hip_bfloat16* __restrict__ w2T,
                                              __hip_bfloat16* __restrict__ xb) {
  const int id = blockIdx.x;
  if (id >= 8192) {                     // x f32 -> bf16
    const size_t base = ((size_t)(id - 8192) * 256 + threadIdx.x) * 8;
    float4 a = *reinterpret_cast<const float4*>(x + base);
    float4 b = *reinterpret_cast<const float4*>(x + base + 4);
    bf16x8 o;
    o[0] = (__bf16)a.x; o[1] = (__bf16)a.y; o[2] = (__bf16)a.z; o[3] = (__bf16)a.w;
    o[4] = (__bf16)b.x; o[5] = (__bf16)b.y; o[6] = (__bf16)b.z; o[7] = (__bf16)b.w;
    *reinterpret_cast<bf16x8*>(xb + base) = o;
    return;
  }
  const float* W; __hip_bfloat16* WT; int K, N, kb, nb;
  if (id < 3072)      { W = w_qkv; WT = wqT; K = 1024; N = 3072; kb = id & 31;          nb = id >> 5; }
  else if (id < 4096) { W = w_out; WT = woT; K = 1024; N = 1024; kb = (id - 3072) & 31; nb = (id - 3072) >> 5; }
  else if (id < 6144) { W = w1;    WT = w1T; K = 1024; N = 2048; kb = (id - 4096) & 31; nb = (id - 4096) >> 5; }
  else                { W = w2;    WT = w2T; K = 2048; N = 1024; kb = (id - 6144) & 63; nb = (id - 6144) >> 6; }
  __shared__ float tsm[32][33];
  const int k0 = kb * 32, n0 = nb * 32;
  const int c = threadIdx.x & 31, r = threadIdx.x >> 5;
#pragma unroll
  for (int i = 0; i < 4; ++i)
    tsm[r + 8 * i][c] = W[(size_t)(k0 + r + 8 * i) * N + n0 + c];
  __syncthreads();
#pragma unroll
  for (int i = 0; i < 4; ++i)
    WT[(size_t)(n0 + r + 8 * i) * K + k0 + c] = __float2bfloat16(tsm[c][r + 8 * i]);
}

// ---------------- GEMM v2: BK=64, both-sides XOR swizzle, XCD block swizzle ----------------
template<int EPI, int OUTB, int HASRES, int BN>
__global__ __launch_bounds__(256) void gemm2(const __hip_bfloat16* __restrict__ A,
                                             const __hip_bfloat16* __restrict__ BT,
                                             const float* __restrict__ bias,
                                             float* __restrict__ Cf,
                                             __hip_bfloat16* __restrict__ Cb,
                                             const float* __restrict__ RESF,
                                             const __hip_bfloat16* __restrict__ RESB,
                                             int M, int N, int K) {
  constexpr int MI = (BN == 128) ? 4 : 2;
  __shared__ __align__(16) __hip_bfloat16 As[128 * 64];
  __shared__ __align__(16) __hip_bfloat16 Bs[BN * 64];
  const int tid  = threadIdx.x;
  const int lane = tid & 63, wave = tid >> 6;
  const int wr = (BN == 128) ? (wave >> 1) : wave;
  const int wc = (BN == 128) ? (wave & 1) : 0;
  const int lr = lane & 15, lq = lane >> 4;
  unsigned g = blockIdx.y * gridDim.x + blockIdx.x;
  const unsigned cpx = (gridDim.x * gridDim.y) >> 3;
  g = (g & 7) * cpx + (g >> 3);
  const int bm0 = (int)(g / gridDim.x) * 128;
  const int bn0 = (int)(g % gridDim.x) * BN;
  f32x4 acc[MI][4] = {};

  for (int k0 = 0; k0 < K; k0 += 64) {
#pragma unroll
    for (int j = 0; j < 4; ++j) {
      const int cbase = j * 256 + wave * 64;
      const int c = cbase + lane;
      const int row = c >> 3, slot = c & 7;
      GLD16(A + (size_t)(bm0 + row) * K + k0 + ((slot ^ (row & 7)) * 8),
            (char*)As + cbase * 16);
    }
#pragma unroll
    for (int j = 0; j < BN / 32; ++j) {
      const int cbase = j * 256 + wave * 64;
      const int c = cbase + lane;
      const int row = c >> 3, slot = c & 7;
      GLD16(BT + (size_t)(bn0 + row) * K + k0 + ((slot ^ (row & 7)) * 8),
            (char*)Bs + cbase * 16);
    }
    __syncthreads();
#pragma unroll
    for (int kk = 0; kk < 2; ++kk) {
      const int co = (kk * 64 + lq * 16) ^ ((lr & 7) << 4);
      bf16x8 af[MI], bfr[4];
#pragma unroll
      for (int i = 0; i < MI; ++i)
        af[i] = *reinterpret_cast<const bf16x8*>(
            (const char*)As + (wr * (MI * 16) + i * 16 + lr) * 128 + co);
#pragma unroll
      for (int i = 0; i < 4; ++i)
        bfr[i] = *reinterpret_cast<const bf16x8*>(
            (const char*)Bs + (wc * 64 + i * 16 + lr) * 128 + co);
#pragma unroll
      for (int mi = 0; mi < MI; ++mi)
#pragma unroll
        for (int ni = 0; ni < 4; ++ni)
          acc[mi][ni] = __builtin_amdgcn_mfma_f32_16x16x32_bf16(af[mi], bfr[ni], acc[mi][ni], 0, 0, 0);
    }
    __syncthreads();
  }

#pragma unroll
  for (int mi = 0; mi < MI; ++mi) {
#pragma unroll
    for (int ni = 0; ni < 4; ++ni) {
      const int col = bn0 + wc * 64 + ni * 16 + lr;
      const float bv = (EPI >= 1) ? bias[col] : 0.0f;
#pragma unroll
      for (int j = 0; j < 4; ++j) {
        const int row = bm0 + wr * (MI * 16) + mi * 16 + lq * 4 + j;
        float v = acc[mi][ni][j] + bv;
        if (HASRES == 1) v += RESF[(size_t)row * N + col];
        if (HASRES == 2) v += __bfloat162float(RESB[(size_t)row * N + col]);
        if (EPI == 2) {
          // tanh-GELU via HW exp2/rcp: gelu(x) = x*e/(e+1), e = exp2(x*(A+B*x^2))
          const float vc = fminf(v, 8.0f);
          const float e2 = __builtin_amdgcn_exp2f(vc * fmaf(vc * vc, 0.1029433f, 2.3022082f));
          v = v * e2 * __builtin_amdgcn_rcpf(e2 + 1.0f);
        }
        if (OUTB) Cb[(size_t)row * N + col] = __float2bfloat16(v);
        else      Cf[(size_t)row * N + col] = v;
      }
    }
  }
}

// ---------------- causal flash attention (r13 structure + explicit DMA fence) ----------------
// Block: 32 q-rows, 4 waves split-K round-robin (KVBLK=32), no in-loop barriers.
// Swapped QK (lane owns one q-row); K prefetched in regs one tile ahead;
// V staged ROW-major per wave via global_load_lds (async DMA, conflict-free);
// >>> s_waitcnt vmcnt(0) fence before PV reads: guarantees the V DMA has landed
// before ds_read consumption AND before the post-loop partial writes reuse the
// same LDS region (the r17 post-timing divergence was this unfenced race). <<<

#define DIAG_MASK(sv)                                                               \
  _Pragma("unroll")                                                                 \
  for (int r = 0; r < 16; ++r) {                                                    \
    const int kl = (r & 3) + 8 * (r >> 2) + 4 * hi;                                 \
    if (kl > lq32) sv[r] = -1e30f;                                                  \
  }

#define PV_HALF(wl0, wl1, wh0, wh1, ksg)                                            \
  {                                                                                 \
    unsigned t0_ = hi ? (wl0) : (wh0);                                              \
    unsigned t1_ = hi ? (wl1) : (wh1);                                              \
    t0_ = (unsigned)__shfl_xor((int)t0_, 32);                                       \
    t1_ = (unsigned)__shfl_xor((int)t1_, 32);                                       \
    u32x4 fw;                                                                       \
    fw[0] = hi ? t0_ : (wl0);  fw[1] = hi ? t1_ : (wl1);                            \
    fw[2] = hi ? (wh0) : t0_;  fw[3] = hi ? (wh1) : t1_;                            \
    bf16x8 pfb = __builtin_bit_cast(bf16x8, fw);                                    \
    const int krow_ = (ksg) * 16 + 8 * hi;                                          \
    bf16x8 vA, vB;                                                                  \
    _Pragma("unroll")                                                               \
    for (int j_ = 0; j_ < 8; ++j_) {                                                \
      vA[j_] = VwB[(krow_ + j_) * 64 + lq32];                                       \
      vB[j_] = VwB[(krow_ + j_) * 64 + 32 + lq32];                                  \
    }                                                                               \
    __builtin_amdgcn_s_setprio(1);                                                  \
    o0 = __builtin_amdgcn_mfma_f32_32x32x16_bf16(vA, pfb, o0, 0, 0, 0);             \
    o1 = __builtin_amdgcn_mfma_f32_32x32x16_bf16(vB, pfb, o1, 0, 0, 0);             \
    __builtin_amdgcn_s_setprio(0);                                                  \
  }

__global__ __launch_bounds__(256, 4) void attn_k(const __hip_bfloat16* __restrict__ qkv,
                                                 __hip_bfloat16* __restrict__ outb) {
  __shared__ __align__(16) char smem[4 * 4096 + 2048];
  // XCD-aware swizzle: xcd = bid%8 owns 4 heads; heavy q-blocks dispatched first
  const int bid = blockIdx.x;
  const int seq = bid >> 3;
  const int bh  = (bid & 7) * 4 + (seq & 3);     // 0..31
  const int qt32 = 63 - (seq >> 2);              // 0..63, heavy first
  const int b = bh >> 4, h = bh & 15;
  const int qb = qt32 * 32;
  const int tid = threadIdx.x;
  const int lane = tid & 63, wave = tid >> 6;
  const int lq32 = lane & 31, hi = lane >> 5;
  const size_t rowbase = (size_t)(b * L_SEQ) * QKV_LD;
  char* const Vw = smem + wave * 4096;           // wave slice: V rows / bf16 O^T partials
  const __bf16* const VwB = (const __bf16*)Vw;
  float* const ML = (float*)(smem + 16384);

  // Q B-frags: lane holds Q[qb+lq32][16c + 8hi + j]
  bf16x8 qf[4];
  {
    const __hip_bfloat16* qp = qkv + rowbase + (size_t)(qb + lq32) * QKV_LD + h * HDIM + 8 * hi;
#pragma unroll
    for (int c = 0; c < 4; ++c) qf[c] = *reinterpret_cast<const bf16x8*>(qp + 16 * c);
  }

  f32x16 o0 = {}, o1 = {};
  float m = -1e30f, lsum = 0.0f;

  int t = wave;
  bf16x8 kr0, kr1, kr2, kr3;
  if (t <= qt32) {                               // prime K regs for first tile
    const __hip_bfloat16* kp = qkv + rowbase + (size_t)(t * 32 + lq32) * QKV_LD + DM + h * HDIM + 8 * hi;
    kr0 = *reinterpret_cast<const bf16x8*>(kp);
    kr1 = *reinterpret_cast<const bf16x8*>(kp + 16);
    kr2 = *reinterpret_cast<const bf16x8*>(kp + 32);
    kr3 = *reinterpret_cast<const bf16x8*>(kp + 48);
  }

  for (; t <= qt32; t += 4) {
    const int k0 = t * 32;
    const bool pf = (t + 4 <= qt32);
    // ---- prefetch next K tile into regs (consumed next iter) ----
    bf16x8 kn0, kn1, kn2, kn3;
    if (pf) {
      const __hip_bfloat16* kp = qkv + rowbase + (size_t)(k0 + 128 + lq32) * QKV_LD + DM + h * HDIM + 8 * hi;
      kn0 = *reinterpret_cast<const bf16x8*>(kp);
      kn1 = *reinterpret_cast<const bf16x8*>(kp + 16);
      kn2 = *reinterpret_cast<const bf16x8*>(kp + 32);
      kn3 = *reinterpret_cast<const bf16x8*>(kp + 48);
    }
    // ---- V rows -> wave-private LDS via async DMA (linear, conflict-free) ----
#pragma unroll
    for (int p = 0; p < 4; ++p)
      GLD16(qkv + rowbase + (size_t)(k0 + 8 * p + (lane >> 3)) * QKV_LD + 2 * DM + h * HDIM + (lane & 7) * 8,
            Vw + p * 1024);
    // ---- QK ----
    f32x16 s = {};
    __builtin_amdgcn_s_setprio(1);
    s = __builtin_amdgcn_mfma_f32_32x32x16_bf16(kr0, qf[0], s, 0, 0, 0);
    s = __builtin_amdgcn_mfma_f32_32x32x16_bf16(kr1, qf[1], s, 0, 0, 0);
    s = __builtin_amdgcn_mfma_f32_32x32x16_bf16(kr2, qf[2], s, 0, 0, 0);
    s = __builtin_amdgcn_mfma_f32_32x32x16_bf16(kr3, qf[3], s, 0, 0, 0);
    __builtin_amdgcn_s_setprio(0);
    if (t == qt32) { DIAG_MASK(s) }
    // ---- online softmax (tree max, defer-rescale THR) ----
    float a0 = fmaxf(s[0], s[1]),   a1 = fmaxf(s[2], s[3]);
    float a2 = fmaxf(s[4], s[5]),   a3 = fmaxf(s[6], s[7]);
    float a4 = fmaxf(s[8], s[9]),   a5 = fmaxf(s[10], s[11]);
    float a6 = fmaxf(s[12], s[13]), a7 = fmaxf(s[14], s[15]);
    a0 = fmaxf(a0, a1); a2 = fmaxf(a2, a3); a4 = fmaxf(a4, a5); a6 = fmaxf(a6, a7);
    float tm = fmaxf(fmaxf(a0, a2), fmaxf(a4, a6));
    tm = fmaxf(tm, __shfl_xor(tm, 32));
    if (!__all(tm <= m + DTHR)) {
      const float mn = fmaxf(m, tm);
      const float fac = __builtin_amdgcn_exp2f((m - mn) * RL);
      m = mn; lsum *= fac; o0 *= fac; o1 *= fac;
    }
    const float mneg = -m * RL;
    float rs = 0.0f;
#pragma unroll
    for (int r = 0; r < 16; ++r) {
      s[r] = __builtin_amdgcn_exp2f(fmaf(s[r], RL, mneg));
      rs += s[r];
    }
    rs += __shfl_xor(rs, 32);
    lsum += rs;
    // ---- P pack ----
    unsigned w0 = pack2(s[0], s[1]),   w1 = pack2(s[2], s[3]);
    unsigned w2 = pack2(s[4], s[5]),   w3 = pack2(s[6], s[7]);
    unsigned w4 = pack2(s[8], s[9]),   w5 = pack2(s[10], s[11]);
    unsigned w6 = pack2(s[12], s[13]), w7 = pack2(s[14], s[15]);
    // ---- FENCE: V DMA must have landed before PV ds_reads (and before the
    //      post-loop partial ds_writes reuse this LDS region). In-order vmcnt
    //      retirement also completes the kn prefetch (needed next iter anyway).
    asm volatile("s_waitcnt vmcnt(0)" ::: "memory");
    // ---- PV ----
    PV_HALF(w0, w1, w2, w3, 0)
    PV_HALF(w4, w5, w6, w7, 1)
    if (pf) { kr0 = kn0; kr1 = kn1; kr2 = kn2; kr3 = kn3; }
  }

  // ---- write partials (bf16 O^T into own slice; m,l) ----
  {
    __bf16* Ow = (__bf16*)Vw;
#pragma unroll
    for (int r = 0; r < 16; ++r) {
      const int d0 = (r & 3) + 8 * (r >> 2) + 4 * hi;
      Ow[d0 * 32 + lq32] = (__bf16)o0[r];
      Ow[(d0 + 32) * 32 + lq32] = (__bf16)o1[r];
    }
    if (hi == 0) {
      ML[wave * 128 + lq32] = m;
      ML[wave * 128 + 64 + lq32] = lsum;
    }
  }
  __syncthreads();

  // ---- combine 4 partials; each thread: one q (tid&31), 8 d's ----
  {
    const int q = tid & 31, dg = tid >> 5;    // dg 0..7
    const float m0 = ML[q], m1 = ML[128 + q], m2 = ML[256 + q], m3 = ML[384 + q];
    const float M = fmaxf(fmaxf(m0, m1), fmaxf(m2, m3));
    const float c0 = __builtin_amdgcn_exp2f((m0 - M) * RL);
    const float c1 = __builtin_amdgcn_exp2f((m1 - M) * RL);
    const float c2 = __builtin_amdgcn_exp2f((m2 - M) * RL);
    const float c3 = __builtin_amdgcn_exp2f((m3 - M) * RL);
    const float l = c0 * ML[64 + q] + c1 * ML[192 + q] + c2 * ML[320 + q] + c3 * ML[448 + q];
    const float inv = 1.0f / l;
    const __bf16* OB = (const __bf16*)smem;
    bf16x8 ov;
#pragma unroll
    for (int i = 0; i < 8; ++i) {
      const int idx = (dg * 8 + i) * 32 + q;
      const float v = c0 * (float)OB[idx] + c1 * (float)OB[2048 + idx]
                    + c2 * (float)OB[4096 + idx] + c3 * (float)OB[6144 + idx];
      ov[i] = (__bf16)(v * inv);
    }
    *reinterpret_cast<bf16x8*>(outb + (size_t)(b * L_SEQ + qb + q) * DM + h * HDIM + dg * 8) = ov;
  }
}

// ---------------- LayerNorm: Y = LN(X) * g + be. INB: bf16 input. OUTB2: bf16 out ----
template<int INB, int OUTB2>
__global__ __launch_bounds__(256) void ln_k(const void* __restrict__ Xv,
                                            const float* __restrict__ g,
                                            const float* __restrict__ be,
                                            float* __restrict__ Y,
                                            __hip_bfloat16* __restrict__ Yb) {
  const int row = blockIdx.x;
  const int tid = threadIdx.x;
  const int lane = tid & 63, wave = tid >> 6;
  float v0, v1, v2, v3;
  if (INB) {
    const __bf16* X = (const __bf16*)Xv;
    bf16x4 x4 = *reinterpret_cast<const bf16x4*>(X + (size_t)row * DM + tid * 4);
    v0 = (float)x4[0]; v1 = (float)x4[1]; v2 = (float)x4[2]; v3 = (float)x4[3];
  } else {
    const float* X = (const float*)Xv;
    float4 x4 = *reinterpret_cast<const float4*>(X + (size_t)row * DM + tid * 4);
    v0 = x4.x; v1 = x4.y; v2 = x4.z; v3 = x4.w;
  }
  float s  = v0 + v1 + v2 + v3;
  float ss = v0 * v0 + v1 * v1 + v2 * v2 + v3 * v3;
#pragma unroll
  for (int off = 1; off < 64; off <<= 1) {
    s  += __shfl_xor(s, off);
    ss += __shfl_xor(ss, off);
  }
  __shared__ float red[8];
  if (lane == 0) { red[wave] = s; red[4 + wave] = ss; }
  __syncthreads();
  float S  = red[0] + red[1] + red[2] + red[3];
  float SS = red[4] + red[5] + red[6] + red[7];
  float mu  = S * (1.0f / DM);
  float var = SS * (1.0f / DM) - mu * mu;
  float rsd = rsqrtf(var + 1e-5f);
  float4 gv = *reinterpret_cast<const float4*>(g + tid * 4);
  float4 bv = *reinterpret_cast<const float4*>(be + tid * 4);
  float4 y;
  y.x = (v0 - mu) * rsd * gv.x + bv.x;
  y.y = (v1 - mu) * rsd * gv.y + bv.y;
  y.z = (v2 - mu) * rsd * gv.z + bv.z;
  y.w = (v3 - mu) * rsd * gv.w + bv.w;
  if (OUTB2) {
    bf16x4 yb;
    yb[0] = (__bf16)y.x; yb[1] = (__bf16)y.y; yb[2] = (__bf16)y.z; yb[3] = (__bf16)y.w;
    *reinterpret_cast<bf16x4*>(Yb + (size_t)row * DM + tid * 4) = yb;
  } else {
    *reinterpret_cast<float4*>(Y + (size_t)row * DM + tid * 4) = y;
  }
}

extern "C" void kernel_launch(void* const* d_in, const int* in_sizes, int n_in,
                              void* d_out, int out_size, void* d_ws, size_t ws_size,
                              hipStream_t stream) {
  const float* x     = (const float*)d_in[0];
  const float* w_qkv = (const float*)d_in[1];
  const float* w_out = (const float*)d_in[2];
  const float* w1    = (const float*)d_in[3];
  const float* b1    = (const float*)d_in[4];
  const float* w2    = (const float*)d_in[5];
  const float* b2    = (const float*)d_in[6];
  const float* g1    = (const float*)d_in[7];
  const float* be1   = (const float*)d_in[8];
  const float* g2    = (const float*)d_in[9];
  const float* be2   = (const float*)d_in[10];
  float* outp = (float*)d_out;
  char* base  = (char*)d_ws;
  const int M = NB * L_SEQ;                 // 4096

  // workspace layout (MiB): [0,4)w2T [4,6)woT [6,10)w1T [10,16)wqT [16,24)xb
  // [24,48)qkvb -> [24,40)ffh after qkv dead; [40,48)ln1b; [48,56)projb;
  // [56,64)attnb; [8,16)ffob (w1T/wqT dead by step 6). All lifetimes traced.
  __hip_bfloat16* w2T  = (__hip_bfloat16*)(base + 0);
  __hip_bfloat16* woT  = (__hip_bfloat16*)(base + 4194304);
  __hip_bfloat16* w1T  = (__hip_bfloat16*)(base + 6291456);
  __hip_bfloat16* wqT  = (__hip_bfloat16*)(base + 10485760);
  __hip_bfloat16* xb   = (__hip_bfloat16*)(base + 16777216);
  __hip_bfloat16* qkvb = (__hip_bfloat16*)(base + 25165824);
  __hip_bfloat16* ffh  = (__hip_bfloat16*)(base + 25165824);
  __hip_bfloat16* ln1b = (__hip_bfloat16*)(base + 41943040);
  __hip_bfloat16* projb= (__hip_bfloat16*)(base + 50331648);
  __hip_bfloat16* attnb= (__hip_bfloat16*)(base + 58720256);
  __hip_bfloat16* ffob = (__hip_bfloat16*)(base + 8388608);

  // fused prep: all weight transposes + x convert
  prep_k<<<10240, 256, 0, stream>>>(w_qkv, w_out, w1, w2, x, wqT, woT, w1T, w2T, xb);

  // 1. qkv = x @ w_qkv (bf16)
  gemm2<0, 1, 0, 128><<<dim3(24, 32), 256, 0, stream>>>(xb, wqT, nullptr, nullptr, qkvb, nullptr, nullptr, M, QKV_LD, DM);
  // 2. attention (bf16): 64 q-blocks x 32 bh, XCD-swizzled, DMA-fenced
  attn_k<<<2048, 256, 0, stream>>>(qkvb, attnb);
  // 3. proj = attn @ w_out + x  (bf16 out, bf16 residual; BN=64)
  gemm2<0, 1, 2, 64><<<dim3(16, 32), 256, 0, stream>>>(attnb, woT, nullptr, nullptr, projb, nullptr, xb, M, DM, DM);
  // 4. ln1 = LN(proj)  (bf16 in, bf16 out)
  ln_k<1, 1><<<M, 256, 0, stream>>>(projb, g1, be1, nullptr, ln1b);
  // 5. ffh = gelu(ln1 @ w1 + b1) (bf16; tanh-GELU epilogue)
  gemm2<2, 1, 0, 128><<<dim3(16, 32), 256, 0, stream>>>(ln1b, w1T, b1, nullptr, ffh, nullptr, nullptr, M, 2 * DM, DM);
  // 6. ffo = ffh @ w2 + b2 + ln1 (bf16 out, bf16 residual; BN=64)
  gemm2<1, 1, 2, 64><<<dim3(16, 32), 256, 0, stream>>>(ffh, w2T, b2, nullptr, ffob, nullptr, ln1b, M, DM, 2 * DM);
  // 7. out = LN(ffo)  (bf16 in, f32 out)
  ln_k<1, 0><<<M, 256, 0, stream>>>(ffob, g2, be2, outp, nullptr);
}